// Round 2
// baseline (272.785 us; speedup 1.0000x reference)
//
#include <hip/hip_runtime.h>

#define N_NODES 100000
#define D 128          // feature dim
#define K 16           // neighbors
#define CATK 256       // concat dim (2*D)
#define MB 32          // nodes per block
#define PAD 8
#define LDSW (CATK + PAD)   // 264 bf16 elems -> 528 B row stride
#define ZW 132              // z-staging row stride in floats (528 B)

typedef __attribute__((ext_vector_type(8))) short bf16x8;
typedef __attribute__((ext_vector_type(4))) float f32x4;
typedef __attribute__((ext_vector_type(2))) float f32x2;

__device__ __forceinline__ unsigned short f2bf(float f) {
    union { float f; unsigned u; } v; v.f = f;
    unsigned u = v.u;
    return (unsigned short)((u + 0x7fffu + ((u >> 16) & 1u)) >> 16);  // RNE
}

// pack 4 floats -> 4 fp8 e4m3 bytes
__device__ __forceinline__ unsigned pk4(float a, float b, float c, float d) {
    int w = __builtin_amdgcn_cvt_pk_fp8_f32(a, b, 0, false);
    w = __builtin_amdgcn_cvt_pk_fp8_f32(c, d, w, true);
    return (unsigned)w;
}

// decode 4 fp8 bytes, accumulate into two packed f32x2 accumulators
__device__ __forceinline__ void dec4p(unsigned w, f32x2* a) {
    f32x2 lo = __builtin_amdgcn_cvt_pk_f32_fp8((int)w, false);
    f32x2 hi = __builtin_amdgcn_cvt_pk_f32_fp8((int)w, true);
    a[0] += lo;
    a[1] += hi;
}

// feats f32 -> fp8 table; also Ws [2,256,128] f32 -> Wt [2,128,256] bf16 (transposed)
__global__ void cvt_all(const float* __restrict__ feats, const float* __restrict__ Ws,
                        unsigned* __restrict__ f8, unsigned short* __restrict__ Wt) {
    int tid = blockIdx.x * 256 + threadIdx.x;
    int i = tid * 16;
    if (i < N_NODES * D) {
        const float4* p = (const float4*)(feats + i);
        float4 v0 = p[0], v1 = p[1], v2 = p[2], v3 = p[3];
        uint4 o;
        o.x = pk4(v0.x, v0.y, v0.z, v0.w);
        o.y = pk4(v1.x, v1.y, v1.z, v1.w);
        o.z = pk4(v2.x, v2.y, v2.z, v2.w);
        o.w = pk4(v3.x, v3.y, v3.z, v3.w);
        *(uint4*)(f8 + i / 4) = o;
    }
    if (tid < 2 * CATK * D) {
        int l = tid / (CATK * D);
        int r = tid % (CATK * D);
        int n = r / CATK, k = r % CATK;
        Wt[tid] = f2bf(Ws[l * CATK * D + k * D + n]);
    }
}

// One GraphSAGE layer: gather(fp8)+mean+concat+GEMM(+bias)(+relu)
// LAYER==0: self from f32 feats; outputs h1 bf16 + h1 fp8 (staged epilogue for packing)
// LAYER==1: self from bf16 h1; outputs z f32 directly from accumulators
// launch_bounds(256, 8): 8 blocks/CU (32 waves/CU), VGPR cap 64 -- TLP is the
// latency-hiding lever; gather is 2 batches of 8 in-flight uint4 (32 VGPRs payload).
template <int LAYER>
__launch_bounds__(256, 8)
__global__ void sage_layer(const float* __restrict__ self_f32,
                           const unsigned short* __restrict__ self_bf,
                           const unsigned char* __restrict__ g8,
                           const int* __restrict__ idx,
                           const unsigned short* __restrict__ Wt,
                           const float* __restrict__ bias,
                           unsigned short* __restrict__ h_out,
                           unsigned char* __restrict__ h8_out,
                           float* __restrict__ z_out) {
    __shared__ __align__(16) char smraw[MB * LDSW * 2];   // 16896 B, dual-purpose
    unsigned short (*cat)[LDSW] = (unsigned short (*)[LDSW])smraw;
    float (*zb)[ZW] = (float (*)[ZW])smraw;

    const int t = threadIdx.x;
    const int base = blockIdx.x * MB;
    const int lane = t & 63;
    const int wave = t >> 6;
    const int q = lane >> 4;
    const int nlo = lane & 15;

    // ---- gather(fp8) + mean + self + concat into LDS (bf16) ----
    {
        const int m = t >> 3;            // node in tile
        const int c = (t & 7) * 16;      // 16-element column slice
        const int node = base + m;

        // neighbor indices: 8 lanes share each 16B chunk -> in-wave broadcast
        const int4* ip = (const int4*)(idx + (size_t)node * K);
        int4 i0 = ip[0], i1 = ip[1];

        // self part (overlaps with idx/gather latency)
        if (LAYER == 0) {
            const float4* sp = (const float4*)(self_f32 + (size_t)node * D + c);
            float sv[16];
            *(f32x4*)&sv[0]  = *(const f32x4*)&sp[0];
            *(f32x4*)&sv[4]  = *(const f32x4*)&sp[1];
            *(f32x4*)&sv[8]  = *(const f32x4*)&sp[2];
            *(f32x4*)&sv[12] = *(const f32x4*)&sp[3];
            unsigned w[8];
#pragma unroll
            for (int j = 0; j < 8; ++j)
                w[j] = (unsigned)f2bf(sv[2 * j]) | ((unsigned)f2bf(sv[2 * j + 1]) << 16);
            *(uint4*)&cat[m][c]     = make_uint4(w[0], w[1], w[2], w[3]);
            *(uint4*)&cat[m][c + 8] = make_uint4(w[4], w[5], w[6], w[7]);
        } else {
            const uint4* sp = (const uint4*)(self_bf + (size_t)node * D + c);
            uint4 sb0 = sp[0], sb1 = sp[1];
            *(uint4*)&cat[m][c]     = sb0;
            *(uint4*)&cat[m][c + 8] = sb1;
        }

        const unsigned char* gp = g8 + c;
        f32x2 acc2[8];
#pragma unroll
        for (int j = 0; j < 8; ++j) acc2[j] = (f32x2){0.f, 0.f};

        // batch 1: 8 gathers in flight, then decode
        {
            uint4 u[8];
            u[0] = *(const uint4*)(gp + (size_t)i0.x * D);
            u[1] = *(const uint4*)(gp + (size_t)i0.y * D);
            u[2] = *(const uint4*)(gp + (size_t)i0.z * D);
            u[3] = *(const uint4*)(gp + (size_t)i0.w * D);
            u[4] = *(const uint4*)(gp + (size_t)i1.x * D);
            u[5] = *(const uint4*)(gp + (size_t)i1.y * D);
            u[6] = *(const uint4*)(gp + (size_t)i1.z * D);
            u[7] = *(const uint4*)(gp + (size_t)i1.w * D);
            // issue next idx load while batch-1 data is in flight
            int4 i2 = ip[2], i3 = ip[3];
#pragma unroll
            for (int k = 0; k < 8; ++k) {
                dec4p(u[k].x, acc2 + 0);
                dec4p(u[k].y, acc2 + 2);
                dec4p(u[k].z, acc2 + 4);
                dec4p(u[k].w, acc2 + 6);
            }
            // batch 2
            u[0] = *(const uint4*)(gp + (size_t)i2.x * D);
            u[1] = *(const uint4*)(gp + (size_t)i2.y * D);
            u[2] = *(const uint4*)(gp + (size_t)i2.z * D);
            u[3] = *(const uint4*)(gp + (size_t)i2.w * D);
            u[4] = *(const uint4*)(gp + (size_t)i3.x * D);
            u[5] = *(const uint4*)(gp + (size_t)i3.y * D);
            u[6] = *(const uint4*)(gp + (size_t)i3.z * D);
            u[7] = *(const uint4*)(gp + (size_t)i3.w * D);
#pragma unroll
            for (int k = 0; k < 8; ++k) {
                dec4p(u[k].x, acc2 + 0);
                dec4p(u[k].y, acc2 + 2);
                dec4p(u[k].z, acc2 + 4);
                dec4p(u[k].w, acc2 + 6);
            }
        }

        unsigned pk[8];
#pragma unroll
        for (int j = 0; j < 8; ++j) {
            unsigned short a = f2bf(acc2[j].x * (1.f / 16.f));
            unsigned short b = f2bf(acc2[j].y * (1.f / 16.f));
            pk[j] = (unsigned)a | ((unsigned)b << 16);
        }
        *(uint4*)&cat[m][D + c]     = make_uint4(pk[0], pk[1], pk[2], pk[3]);
        *(uint4*)&cat[m][D + c + 8] = make_uint4(pk[4], pk[5], pk[6], pk[7]);
    }

    // ---- per-wave B fragments (32 output cols, K=256) in VGPRs ----
    bf16x8 bfrag[2][8];
#pragma unroll
    for (int ct = 0; ct < 2; ++ct) {
        int n = wave * 32 + ct * 16 + nlo;
        const unsigned short* wp = Wt + n * CATK + q * 8;
#pragma unroll
        for (int ks = 0; ks < 8; ++ks)
            bfrag[ct][ks] = *(const bf16x8*)(wp + ks * 32);
    }

    __syncthreads();

    // ---- MFMA: [32 x 256] x [256 x 32(this wave)] ----
    f32x4 acc00 = {}, acc01 = {}, acc10 = {}, acc11 = {};
#pragma unroll
    for (int ks = 0; ks < 8; ++ks) {
        bf16x8 a0 = *(const bf16x8*)&cat[nlo][ks * 32 + q * 8];
        bf16x8 a1 = *(const bf16x8*)&cat[16 + nlo][ks * 32 + q * 8];
        acc00 = __builtin_amdgcn_mfma_f32_16x16x32_bf16(a0, bfrag[0][ks], acc00, 0, 0, 0);
        acc01 = __builtin_amdgcn_mfma_f32_16x16x32_bf16(a0, bfrag[1][ks], acc01, 0, 0, 0);
        acc10 = __builtin_amdgcn_mfma_f32_16x16x32_bf16(a1, bfrag[0][ks], acc10, 0, 0, 0);
        acc11 = __builtin_amdgcn_mfma_f32_16x16x32_bf16(a1, bfrag[1][ks], acc11, 0, 0, 0);
    }

    if (LAYER == 1) {
        // ---- direct f32 store from accumulator layout (no LDS staging, no barriers) ----
        // C/D layout: col = lane&15 (+ct*16+wave*32), row = q*4 + r
#pragma unroll
        for (int ct = 0; ct < 2; ++ct) {
            int col = wave * 32 + ct * 16 + nlo;
            float bv = bias[col];
            f32x4 v0 = (ct == 0) ? acc00 : acc01;
            f32x4 v1 = (ct == 0) ? acc10 : acc11;
#pragma unroll
            for (int r = 0; r < 4; ++r) {
                z_out[(size_t)(base + q * 4 + r) * D + col]      = v0[r] + bv;
                z_out[(size_t)(base + 16 + q * 4 + r) * D + col] = v1[r] + bv;
            }
        }
        return;
    }

    // ---- LAYER 0: stage z tile into LDS (reusing cat's memory) for col-pair packing ----
    __syncthreads();  // all A-fragment reads done; safe to overwrite
#pragma unroll
    for (int ct = 0; ct < 2; ++ct) {
        int col = wave * 32 + ct * 16 + nlo;
        float bv = bias[col];
        f32x4 v0 = (ct == 0) ? acc00 : acc01;
        f32x4 v1 = (ct == 0) ? acc10 : acc11;
#pragma unroll
        for (int r = 0; r < 4; ++r) {
            zb[q * 4 + r][col]      = v0[r] + bv;
            zb[16 + q * 4 + r][col] = v1[r] + bv;
        }
    }
    __syncthreads();
    {
        const int m = t >> 3;
        const int c = (t & 7) * 16;
        float x[16];
        *(f32x4*)&x[0]  = *(const f32x4*)&zb[m][c];
        *(f32x4*)&x[4]  = *(const f32x4*)&zb[m][c + 4];
        *(f32x4*)&x[8]  = *(const f32x4*)&zb[m][c + 8];
        *(f32x4*)&x[12] = *(const f32x4*)&zb[m][c + 12];
        size_t go = (size_t)(base + m) * D + c;
#pragma unroll
        for (int i = 0; i < 16; ++i) x[i] = x[i] > 0.f ? x[i] : 0.f;
        unsigned wb[8];
#pragma unroll
        for (int j = 0; j < 8; ++j)
            wb[j] = (unsigned)f2bf(x[2 * j]) | ((unsigned)f2bf(x[2 * j + 1]) << 16);
        uint4* hp = (uint4*)(h_out + go);
        hp[0] = make_uint4(wb[0], wb[1], wb[2], wb[3]);
        hp[1] = make_uint4(wb[4], wb[5], wb[6], wb[7]);
        uint4 o8;
        o8.x = pk4(x[0], x[1], x[2], x[3]);
        o8.y = pk4(x[4], x[5], x[6], x[7]);
        o8.z = pk4(x[8], x[9], x[10], x[11]);
        o8.w = pk4(x[12], x[13], x[14], x[15]);
        *(uint4*)(h8_out + go) = o8;
    }
}

extern "C" void kernel_launch(void* const* d_in, const int* in_sizes, int n_in,
                              void* d_out, int out_size, void* d_ws, size_t ws_size,
                              hipStream_t stream) {
    const float* feats = (const float*)d_in[0];
    const int* neigh   = (const int*)d_in[1];
    const float* Ws    = (const float*)d_in[2];
    const float* bs    = (const float*)d_in[3];
    float* out = (float*)d_out;

    char* ws = (char*)d_ws;
    unsigned short* h1_bf  = (unsigned short*)(ws);                 // 25,600,000 B
    unsigned char*  feats8 = (unsigned char*)(ws + 25600000);       // 12,800,000 B
    unsigned char*  h18    = (unsigned char*)(ws + 38400000);       // 12,800,000 B
    unsigned short* Wt     = (unsigned short*)(ws + 51200000);      //    131,072 B

    cvt_all<<<3125, 256, 0, stream>>>(feats, Ws, (unsigned*)feats8, Wt);

    sage_layer<0><<<N_NODES / MB, 256, 0, stream>>>(
        feats, nullptr, feats8, neigh, Wt, bs, h1_bf, h18, nullptr);
    sage_layer<1><<<N_NODES / MB, 256, 0, stream>>>(
        nullptr, h1_bf, h18, neigh + N_NODES * K, Wt + CATK * D, bs + D,
        nullptr, nullptr, out);
}

// Round 4
// 219.489 us; speedup vs baseline: 1.2428x; 1.2428x over previous
//
#include <hip/hip_runtime.h>

#define N_NODES 100000
#define D 128          // feature dim
#define K 16           // neighbors
#define CATK 256       // concat dim (2*D)
#define MB 32          // nodes per block
#define PAD 8
#define LDSW (CATK + PAD)   // 264 bf16 elems -> 528 B row stride
#define ZW 132              // z-staging row stride in floats (528 B)

typedef __attribute__((ext_vector_type(8))) short bf16x8;
typedef __attribute__((ext_vector_type(4))) float f32x4;
typedef __attribute__((ext_vector_type(2))) float f32x2;

__device__ __forceinline__ unsigned short f2bf(float f) {
    union { float f; unsigned u; } v; v.f = f;
    unsigned u = v.u;
    return (unsigned short)((u + 0x7fffu + ((u >> 16) & 1u)) >> 16);  // RNE
}

// pack 4 floats -> 4 fp8 e4m3 bytes
__device__ __forceinline__ unsigned pk4(float a, float b, float c, float d) {
    int w = __builtin_amdgcn_cvt_pk_fp8_f32(a, b, 0, false);
    w = __builtin_amdgcn_cvt_pk_fp8_f32(c, d, w, true);
    return (unsigned)w;
}

// decode 4 fp8 bytes, accumulate into two packed f32x2 accumulators
__device__ __forceinline__ void dec4p(unsigned w, f32x2* a) {
    f32x2 lo = __builtin_amdgcn_cvt_pk_f32_fp8((int)w, false);
    f32x2 hi = __builtin_amdgcn_cvt_pk_f32_fp8((int)w, true);
    a[0] += lo;
    a[1] += hi;
}

// feats f32 -> fp8 table; also Ws [2,256,128] f32 -> Wt [2,128,256] bf16 (transposed)
__global__ void cvt_all(const float* __restrict__ feats, const float* __restrict__ Ws,
                        unsigned* __restrict__ f8, unsigned short* __restrict__ Wt) {
    int tid = blockIdx.x * 256 + threadIdx.x;
    int i = tid * 16;
    if (i < N_NODES * D) {
        const float4* p = (const float4*)(feats + i);
        float4 v0 = p[0], v1 = p[1], v2 = p[2], v3 = p[3];
        uint4 o;
        o.x = pk4(v0.x, v0.y, v0.z, v0.w);
        o.y = pk4(v1.x, v1.y, v1.z, v1.w);
        o.z = pk4(v2.x, v2.y, v2.z, v2.w);
        o.w = pk4(v3.x, v3.y, v3.z, v3.w);
        *(uint4*)(f8 + i / 4) = o;
    }
    if (tid < 2 * CATK * D) {
        int l = tid / (CATK * D);
        int r = tid % (CATK * D);
        int n = r / CATK, k = r % CATK;
        Wt[tid] = f2bf(Ws[l * CATK * D + k * D + n]);
    }
}

// One GraphSAGE layer: gather(fp8)+mean+concat+GEMM(+bias)(+relu)
// LAYER==0: self from f32 feats; outputs h1 bf16 + h1 fp8 (staged epilogue for packing)
// LAYER==1: self from bf16 h1; outputs z f32 directly from accumulators
// launch_bounds(256, 6): 6 blocks/CU (24 waves/CU, 75% cap), VGPR cap ~85.
// (256,8)/cap-64 spilled catastrophically (R2: WRITE_SIZE 37->165MB);
// (256,4)/cap-128 left occupancy at 42% (R1). Cap 85 is the sweet spot:
// 2x8-batch gather payload (32 VGPRs) + working set fits without spill.
template <int LAYER>
__launch_bounds__(256, 6)
__global__ void sage_layer(const float* __restrict__ self_f32,
                           const unsigned short* __restrict__ self_bf,
                           const unsigned char* __restrict__ g8,
                           const int* __restrict__ idx,
                           const unsigned short* __restrict__ Wt,
                           const float* __restrict__ bias,
                           unsigned short* __restrict__ h_out,
                           unsigned char* __restrict__ h8_out,
                           float* __restrict__ z_out) {
    __shared__ __align__(16) char smraw[MB * LDSW * 2];   // 16896 B, dual-purpose
    unsigned short (*cat)[LDSW] = (unsigned short (*)[LDSW])smraw;
    float (*zb)[ZW] = (float (*)[ZW])smraw;

    const int t = threadIdx.x;
    const int base = blockIdx.x * MB;
    const int lane = t & 63;
    const int wave = t >> 6;
    const int q = lane >> 4;
    const int nlo = lane & 15;

    // ---- gather(fp8) + mean + self + concat into LDS (bf16) ----
    {
        const int m = t >> 3;            // node in tile
        const int c = (t & 7) * 16;      // 16-element column slice
        const int node = base + m;

        // neighbor indices: 8 lanes share each 16B chunk -> in-wave broadcast
        const int4* ip = (const int4*)(idx + (size_t)node * K);
        int4 i0 = ip[0], i1 = ip[1];

        // self part (overlaps with idx/gather latency)
        if (LAYER == 0) {
            const float4* sp = (const float4*)(self_f32 + (size_t)node * D + c);
            float sv[16];
            *(f32x4*)&sv[0]  = *(const f32x4*)&sp[0];
            *(f32x4*)&sv[4]  = *(const f32x4*)&sp[1];
            *(f32x4*)&sv[8]  = *(const f32x4*)&sp[2];
            *(f32x4*)&sv[12] = *(const f32x4*)&sp[3];
            unsigned w[8];
#pragma unroll
            for (int j = 0; j < 8; ++j)
                w[j] = (unsigned)f2bf(sv[2 * j]) | ((unsigned)f2bf(sv[2 * j + 1]) << 16);
            *(uint4*)&cat[m][c]     = make_uint4(w[0], w[1], w[2], w[3]);
            *(uint4*)&cat[m][c + 8] = make_uint4(w[4], w[5], w[6], w[7]);
        } else {
            const uint4* sp = (const uint4*)(self_bf + (size_t)node * D + c);
            uint4 sb0 = sp[0], sb1 = sp[1];
            *(uint4*)&cat[m][c]     = sb0;
            *(uint4*)&cat[m][c + 8] = sb1;
        }

        const unsigned char* gp = g8 + c;
        f32x2 acc2[8];
#pragma unroll
        for (int j = 0; j < 8; ++j) acc2[j] = (f32x2){0.f, 0.f};

        // batch 1: 8 gathers in flight, then decode
        {
            uint4 u[8];
            u[0] = *(const uint4*)(gp + (size_t)i0.x * D);
            u[1] = *(const uint4*)(gp + (size_t)i0.y * D);
            u[2] = *(const uint4*)(gp + (size_t)i0.z * D);
            u[3] = *(const uint4*)(gp + (size_t)i0.w * D);
            u[4] = *(const uint4*)(gp + (size_t)i1.x * D);
            u[5] = *(const uint4*)(gp + (size_t)i1.y * D);
            u[6] = *(const uint4*)(gp + (size_t)i1.z * D);
            u[7] = *(const uint4*)(gp + (size_t)i1.w * D);
            // issue next idx load while batch-1 data is in flight
            int4 i2 = ip[2], i3 = ip[3];
#pragma unroll
            for (int k = 0; k < 8; ++k) {
                dec4p(u[k].x, acc2 + 0);
                dec4p(u[k].y, acc2 + 2);
                dec4p(u[k].z, acc2 + 4);
                dec4p(u[k].w, acc2 + 6);
            }
            // batch 2
            u[0] = *(const uint4*)(gp + (size_t)i2.x * D);
            u[1] = *(const uint4*)(gp + (size_t)i2.y * D);
            u[2] = *(const uint4*)(gp + (size_t)i2.z * D);
            u[3] = *(const uint4*)(gp + (size_t)i2.w * D);
            u[4] = *(const uint4*)(gp + (size_t)i3.x * D);
            u[5] = *(const uint4*)(gp + (size_t)i3.y * D);
            u[6] = *(const uint4*)(gp + (size_t)i3.z * D);
            u[7] = *(const uint4*)(gp + (size_t)i3.w * D);
#pragma unroll
            for (int k = 0; k < 8; ++k) {
                dec4p(u[k].x, acc2 + 0);
                dec4p(u[k].y, acc2 + 2);
                dec4p(u[k].z, acc2 + 4);
                dec4p(u[k].w, acc2 + 6);
            }
        }

        unsigned pk[8];
#pragma unroll
        for (int j = 0; j < 8; ++j) {
            unsigned short a = f2bf(acc2[j].x * (1.f / 16.f));
            unsigned short b = f2bf(acc2[j].y * (1.f / 16.f));
            pk[j] = (unsigned)a | ((unsigned)b << 16);
        }
        *(uint4*)&cat[m][D + c]     = make_uint4(pk[0], pk[1], pk[2], pk[3]);
        *(uint4*)&cat[m][D + c + 8] = make_uint4(pk[4], pk[5], pk[6], pk[7]);
    }

    // ---- per-wave B fragments (32 output cols, K=256) in VGPRs ----
    bf16x8 bfrag[2][8];
#pragma unroll
    for (int ct = 0; ct < 2; ++ct) {
        int n = wave * 32 + ct * 16 + nlo;
        const unsigned short* wp = Wt + n * CATK + q * 8;
#pragma unroll
        for (int ks = 0; ks < 8; ++ks)
            bfrag[ct][ks] = *(const bf16x8*)(wp + ks * 32);
    }

    __syncthreads();

    // ---- MFMA: [32 x 256] x [256 x 32(this wave)] ----
    f32x4 acc00 = {}, acc01 = {}, acc10 = {}, acc11 = {};
#pragma unroll
    for (int ks = 0; ks < 8; ++ks) {
        bf16x8 a0 = *(const bf16x8*)&cat[nlo][ks * 32 + q * 8];
        bf16x8 a1 = *(const bf16x8*)&cat[16 + nlo][ks * 32 + q * 8];
        acc00 = __builtin_amdgcn_mfma_f32_16x16x32_bf16(a0, bfrag[0][ks], acc00, 0, 0, 0);
        acc01 = __builtin_amdgcn_mfma_f32_16x16x32_bf16(a0, bfrag[1][ks], acc01, 0, 0, 0);
        acc10 = __builtin_amdgcn_mfma_f32_16x16x32_bf16(a1, bfrag[0][ks], acc10, 0, 0, 0);
        acc11 = __builtin_amdgcn_mfma_f32_16x16x32_bf16(a1, bfrag[1][ks], acc11, 0, 0, 0);
    }

    if (LAYER == 1) {
        // ---- direct f32 store from accumulator layout (no LDS staging, no barriers) ----
        // C/D layout: col = lane&15 (+ct*16+wave*32), row = q*4 + r
#pragma unroll
        for (int ct = 0; ct < 2; ++ct) {
            int col = wave * 32 + ct * 16 + nlo;
            float bv = bias[col];
            f32x4 v0 = (ct == 0) ? acc00 : acc01;
            f32x4 v1 = (ct == 0) ? acc10 : acc11;
#pragma unroll
            for (int r = 0; r < 4; ++r) {
                z_out[(size_t)(base + q * 4 + r) * D + col]      = v0[r] + bv;
                z_out[(size_t)(base + 16 + q * 4 + r) * D + col] = v1[r] + bv;
            }
        }
        return;
    }

    // ---- LAYER 0: stage z tile into LDS (reusing cat's memory) for col-pair packing ----
    __syncthreads();  // all A-fragment reads done; safe to overwrite
#pragma unroll
    for (int ct = 0; ct < 2; ++ct) {
        int col = wave * 32 + ct * 16 + nlo;
        float bv = bias[col];
        f32x4 v0 = (ct == 0) ? acc00 : acc01;
        f32x4 v1 = (ct == 0) ? acc10 : acc11;
#pragma unroll
        for (int r = 0; r < 4; ++r) {
            zb[q * 4 + r][col]      = v0[r] + bv;
            zb[16 + q * 4 + r][col] = v1[r] + bv;
        }
    }
    __syncthreads();
    {
        const int m = t >> 3;
        const int c = (t & 7) * 16;
        float x[16];
        *(f32x4*)&x[0]  = *(const f32x4*)&zb[m][c];
        *(f32x4*)&x[4]  = *(const f32x4*)&zb[m][c + 4];
        *(f32x4*)&x[8]  = *(const f32x4*)&zb[m][c + 8];
        *(f32x4*)&x[12] = *(const f32x4*)&zb[m][c + 12];
        size_t go = (size_t)(base + m) * D + c;
#pragma unroll
        for (int i = 0; i < 16; ++i) x[i] = x[i] > 0.f ? x[i] : 0.f;
        unsigned wb[8];
#pragma unroll
        for (int j = 0; j < 8; ++j)
            wb[j] = (unsigned)f2bf(x[2 * j]) | ((unsigned)f2bf(x[2 * j + 1]) << 16);
        uint4* hp = (uint4*)(h_out + go);
        hp[0] = make_uint4(wb[0], wb[1], wb[2], wb[3]);
        hp[1] = make_uint4(wb[4], wb[5], wb[6], wb[7]);
        uint4 o8;
        o8.x = pk4(x[0], x[1], x[2], x[3]);
        o8.y = pk4(x[4], x[5], x[6], x[7]);
        o8.z = pk4(x[8], x[9], x[10], x[11]);
        o8.w = pk4(x[12], x[13], x[14], x[15]);
        *(uint4*)(h8_out + go) = o8;
    }
}

extern "C" void kernel_launch(void* const* d_in, const int* in_sizes, int n_in,
                              void* d_out, int out_size, void* d_ws, size_t ws_size,
                              hipStream_t stream) {
    const float* feats = (const float*)d_in[0];
    const int* neigh   = (const int*)d_in[1];
    const float* Ws    = (const float*)d_in[2];
    const float* bs    = (const float*)d_in[3];
    float* out = (float*)d_out;

    char* ws = (char*)d_ws;
    unsigned short* h1_bf  = (unsigned short*)(ws);                 // 25,600,000 B
    unsigned char*  feats8 = (unsigned char*)(ws + 25600000);       // 12,800,000 B
    unsigned char*  h18    = (unsigned char*)(ws + 38400000);       // 12,800,000 B
    unsigned short* Wt     = (unsigned short*)(ws + 51200000);      //    131,072 B

    cvt_all<<<3125, 256, 0, stream>>>(feats, Ws, (unsigned*)feats8, Wt);

    sage_layer<0><<<N_NODES / MB, 256, 0, stream>>>(
        feats, nullptr, feats8, neigh, Wt, bs, h1_bf, h18, nullptr);
    sage_layer<1><<<N_NODES / MB, 256, 0, stream>>>(
        nullptr, h1_bf, h18, neigh + N_NODES * K, Wt + CATK * D, bs + D,
        nullptr, nullptr, out);
}

// Round 5
// 201.446 us; speedup vs baseline: 1.3541x; 1.0896x over previous
//
#include <hip/hip_runtime.h>

#define N_NODES 100000
#define D 128          // feature dim
#define K 16           // neighbors
#define CATK 256       // concat dim (2*D)
#define MB 32          // nodes per block
#define PAD 8
#define LDSW (CATK + PAD)   // 264 bf16 elems -> 528 B row stride
#define ZW 132              // z-staging row stride in floats (528 B)

typedef __attribute__((ext_vector_type(8))) short bf16x8;
typedef __attribute__((ext_vector_type(4))) float f32x4;
typedef __attribute__((ext_vector_type(2))) float f32x2;
typedef __attribute__((ext_vector_type(4))) unsigned u32x4;

// raw 16B global load: issued immediately, NOT waited -- caller manages vmcnt.
#define GLOAD(dst, addr) \
    asm volatile("global_load_dwordx4 %0, %1, off" : "=v"(dst) : "v"(addr))

// counted wait + scheduling fence (rule #18: SB stops VALU hoisting above the wait)
#define WAITVM(n)                                            \
    do {                                                     \
        asm volatile("s_waitcnt vmcnt(" #n ")" ::: "memory"); \
        __builtin_amdgcn_sched_barrier(0);                   \
    } while (0)

__device__ __forceinline__ unsigned short f2bf(float f) {
    union { float f; unsigned u; } v; v.f = f;
    unsigned u = v.u;
    return (unsigned short)((u + 0x7fffu + ((u >> 16) & 1u)) >> 16);  // RNE
}

// pack 4 floats -> 4 fp8 e4m3 bytes
__device__ __forceinline__ unsigned pk4(float a, float b, float c, float d) {
    int w = __builtin_amdgcn_cvt_pk_fp8_f32(a, b, 0, false);
    w = __builtin_amdgcn_cvt_pk_fp8_f32(c, d, w, true);
    return (unsigned)w;
}

// decode 4 fp8 bytes, accumulate into two packed f32x2 accumulators
__device__ __forceinline__ void dec4p(unsigned w, f32x2* a) {
    f32x2 lo = __builtin_amdgcn_cvt_pk_f32_fp8((int)w, false);
    f32x2 hi = __builtin_amdgcn_cvt_pk_f32_fp8((int)w, true);
    a[0] += lo;
    a[1] += hi;
}

// feats f32 -> fp8 table; also Ws [2,256,128] f32 -> Wt [2,128,256] bf16 (transposed)
__global__ void cvt_all(const float* __restrict__ feats, const float* __restrict__ Ws,
                        unsigned* __restrict__ f8, unsigned short* __restrict__ Wt) {
    int tid = blockIdx.x * 256 + threadIdx.x;
    int i = tid * 16;
    if (i < N_NODES * D) {
        const float4* p = (const float4*)(feats + i);
        float4 v0 = p[0], v1 = p[1], v2 = p[2], v3 = p[3];
        uint4 o;
        o.x = pk4(v0.x, v0.y, v0.z, v0.w);
        o.y = pk4(v1.x, v1.y, v1.z, v1.w);
        o.z = pk4(v2.x, v2.y, v2.z, v2.w);
        o.w = pk4(v3.x, v3.y, v3.z, v3.w);
        *(uint4*)(f8 + i / 4) = o;
    }
    if (tid < 2 * CATK * D) {
        int l = tid / (CATK * D);
        int r = tid % (CATK * D);
        int n = r / CATK, k = r % CATK;
        Wt[tid] = f2bf(Ws[l * CATK * D + k * D + n]);
    }
}

// One GraphSAGE layer: gather(fp8)+mean+concat+GEMM(+bias)(+relu)
// LAYER==0: self from f32 feats; outputs h1 bf16 + h1 fp8 (staged epilogue for packing)
// LAYER==1: self from bf16 h1; outputs z f32 directly from accumulators
//
// launch_bounds(256,4): cap 128 -- the ONLY non-spilling point measured
// ((256,6)/cap85 and (256,8)/cap64 both spilled: WRITE_SIZE 37->81/165MB).
// Gather pipeline is hand-built with inline-asm global_load_dwordx4 + counted
// s_waitcnt vmcnt(N): 4 idx + self + 16 gathers in flight (the compiler refuses
// to hold >2-3 from C++ source; R1 emitted only 48 VGPRs).
template <int LAYER>
__launch_bounds__(256, 4)
__global__ void sage_layer(const float* __restrict__ self_f32,
                           const unsigned short* __restrict__ self_bf,
                           const unsigned char* __restrict__ g8,
                           const int* __restrict__ idx,
                           const unsigned short* __restrict__ Wt,
                           const float* __restrict__ bias,
                           unsigned short* __restrict__ h_out,
                           unsigned char* __restrict__ h8_out,
                           float* __restrict__ z_out) {
    __shared__ __align__(16) char smraw[MB * LDSW * 2];   // 16896 B, dual-purpose
    unsigned short (*cat)[LDSW] = (unsigned short (*)[LDSW])smraw;
    float (*zb)[ZW] = (float (*)[ZW])smraw;

    const int t = threadIdx.x;
    const int base = blockIdx.x * MB;
    const int lane = t & 63;
    const int wave = t >> 6;
    const int q = lane >> 4;
    const int nlo = lane & 15;

    // ---- gather(fp8) + mean + self + concat into LDS (bf16) ----
    {
        const int m = t >> 3;            // node in tile
        const int c = (t & 7) * 16;      // 16-element column slice
        const int node = base + m;

        // --- issue phase: everything in flight, zero waits ---
        // 4x idx (oldest), then self, then (after idx arrives) 16 gathers.
        const char* ipb = (const char*)(idx + (size_t)node * K);
        u32x4 xi0, xi1, xi2, xi3;
        GLOAD(xi0, ipb);
        GLOAD(xi1, ipb + 16);
        GLOAD(xi2, ipb + 32);
        GLOAD(xi3, ipb + 48);

        f32x4 s0, s1, s2, s3;   // LAYER 0 self payload
        u32x4 sb0, sb1;         // LAYER 1 self payload
        if (LAYER == 0) {
            const char* sp = (const char*)(self_f32 + (size_t)node * D + c);
            GLOAD(s0, sp);
            GLOAD(s1, sp + 16);
            GLOAD(s2, sp + 32);
            GLOAD(s3, sp + 48);
        } else {
            const char* sp = (const char*)(self_bf + (size_t)node * D + c);
            GLOAD(sb0, sp);
            GLOAD(sb1, sp + 16);
        }

        // wait for idx only (self still in flight)
        if (LAYER == 0) { WAITVM(4); } else { WAITVM(2); }

        const unsigned char* gp = g8 + c;
        u32x4 g0, g1, g2, g3, g4, g5, g6, g7, g8r, g9, g10, g11, g12, g13, g14, g15;
        GLOAD(g0,  gp + (size_t)xi0[0] * D);
        GLOAD(g1,  gp + (size_t)xi0[1] * D);
        GLOAD(g2,  gp + (size_t)xi0[2] * D);
        GLOAD(g3,  gp + (size_t)xi0[3] * D);
        GLOAD(g4,  gp + (size_t)xi1[0] * D);
        GLOAD(g5,  gp + (size_t)xi1[1] * D);
        GLOAD(g6,  gp + (size_t)xi1[2] * D);
        GLOAD(g7,  gp + (size_t)xi1[3] * D);
        GLOAD(g8r, gp + (size_t)xi2[0] * D);
        GLOAD(g9,  gp + (size_t)xi2[1] * D);
        GLOAD(g10, gp + (size_t)xi2[2] * D);
        GLOAD(g11, gp + (size_t)xi2[3] * D);
        GLOAD(g12, gp + (size_t)xi3[0] * D);
        GLOAD(g13, gp + (size_t)xi3[1] * D);
        GLOAD(g14, gp + (size_t)xi3[2] * D);
        GLOAD(g15, gp + (size_t)xi3[3] * D);

        // self ready (16 gathers still in flight) -> convert + LDS write under flight
        WAITVM(16);
        if (LAYER == 0) {
            float sv[16];
            *(f32x4*)&sv[0] = s0; *(f32x4*)&sv[4] = s1;
            *(f32x4*)&sv[8] = s2; *(f32x4*)&sv[12] = s3;
            unsigned w[8];
#pragma unroll
            for (int j = 0; j < 8; ++j)
                w[j] = (unsigned)f2bf(sv[2 * j]) | ((unsigned)f2bf(sv[2 * j + 1]) << 16);
            *(uint4*)&cat[m][c]     = make_uint4(w[0], w[1], w[2], w[3]);
            *(uint4*)&cat[m][c + 8] = make_uint4(w[4], w[5], w[6], w[7]);
        } else {
            *(u32x4*)&cat[m][c]     = sb0;
            *(u32x4*)&cat[m][c + 8] = sb1;
        }

        f32x2 acc2[8];
#pragma unroll
        for (int j = 0; j < 8; ++j) acc2[j] = (f32x2){0.f, 0.f};

        // oldest 8 gathers ready -> decode while newest 8 still fly
        WAITVM(8);
        {
            const u32x4* gb[8] = {&g0, &g1, &g2, &g3, &g4, &g5, &g6, &g7};
#pragma unroll
            for (int k = 0; k < 8; ++k) {
                dec4p((*gb[k])[0], acc2 + 0);
                dec4p((*gb[k])[1], acc2 + 2);
                dec4p((*gb[k])[2], acc2 + 4);
                dec4p((*gb[k])[3], acc2 + 6);
            }
        }
        WAITVM(0);
        {
            const u32x4* gb[8] = {&g8r, &g9, &g10, &g11, &g12, &g13, &g14, &g15};
#pragma unroll
            for (int k = 0; k < 8; ++k) {
                dec4p((*gb[k])[0], acc2 + 0);
                dec4p((*gb[k])[1], acc2 + 2);
                dec4p((*gb[k])[2], acc2 + 4);
                dec4p((*gb[k])[3], acc2 + 6);
            }
        }

        unsigned pk[8];
#pragma unroll
        for (int j = 0; j < 8; ++j) {
            unsigned short a = f2bf(acc2[j].x * (1.f / 16.f));
            unsigned short b = f2bf(acc2[j].y * (1.f / 16.f));
            pk[j] = (unsigned)a | ((unsigned)b << 16);
        }
        *(uint4*)&cat[m][D + c]     = make_uint4(pk[0], pk[1], pk[2], pk[3]);
        *(uint4*)&cat[m][D + c + 8] = make_uint4(pk[4], pk[5], pk[6], pk[7]);
    }

    // ---- per-wave B fragments (32 output cols, K=256) in VGPRs ----
    bf16x8 bfrag[2][8];
#pragma unroll
    for (int ct = 0; ct < 2; ++ct) {
        int n = wave * 32 + ct * 16 + nlo;
        const unsigned short* wp = Wt + n * CATK + q * 8;
#pragma unroll
        for (int ks = 0; ks < 8; ++ks)
            bfrag[ct][ks] = *(const bf16x8*)(wp + ks * 32);
    }

    __syncthreads();

    // ---- MFMA: [32 x 256] x [256 x 32(this wave)] ----
    f32x4 acc00 = {}, acc01 = {}, acc10 = {}, acc11 = {};
#pragma unroll
    for (int ks = 0; ks < 8; ++ks) {
        bf16x8 a0 = *(const bf16x8*)&cat[nlo][ks * 32 + q * 8];
        bf16x8 a1 = *(const bf16x8*)&cat[16 + nlo][ks * 32 + q * 8];
        acc00 = __builtin_amdgcn_mfma_f32_16x16x32_bf16(a0, bfrag[0][ks], acc00, 0, 0, 0);
        acc01 = __builtin_amdgcn_mfma_f32_16x16x32_bf16(a0, bfrag[1][ks], acc01, 0, 0, 0);
        acc10 = __builtin_amdgcn_mfma_f32_16x16x32_bf16(a1, bfrag[0][ks], acc10, 0, 0, 0);
        acc11 = __builtin_amdgcn_mfma_f32_16x16x32_bf16(a1, bfrag[1][ks], acc11, 0, 0, 0);
    }

    if (LAYER == 1) {
        // ---- direct f32 store from accumulator layout (no LDS staging, no barriers) ----
        // C/D layout: col = lane&15 (+ct*16+wave*32), row = q*4 + r
#pragma unroll
        for (int ct = 0; ct < 2; ++ct) {
            int col = wave * 32 + ct * 16 + nlo;
            float bv = bias[col];
            f32x4 v0 = (ct == 0) ? acc00 : acc01;
            f32x4 v1 = (ct == 0) ? acc10 : acc11;
#pragma unroll
            for (int r = 0; r < 4; ++r) {
                z_out[(size_t)(base + q * 4 + r) * D + col]      = v0[r] + bv;
                z_out[(size_t)(base + 16 + q * 4 + r) * D + col] = v1[r] + bv;
            }
        }
        return;
    }

    // ---- LAYER 0: stage z tile into LDS (reusing cat's memory) for col-pair packing ----
    __syncthreads();  // all A-fragment reads done; safe to overwrite
#pragma unroll
    for (int ct = 0; ct < 2; ++ct) {
        int col = wave * 32 + ct * 16 + nlo;
        float bv = bias[col];
        f32x4 v0 = (ct == 0) ? acc00 : acc01;
        f32x4 v1 = (ct == 0) ? acc10 : acc11;
#pragma unroll
        for (int r = 0; r < 4; ++r) {
            zb[q * 4 + r][col]      = v0[r] + bv;
            zb[16 + q * 4 + r][col] = v1[r] + bv;
        }
    }
    __syncthreads();
    {
        const int m = t >> 3;
        const int c = (t & 7) * 16;
        float x[16];
        *(f32x4*)&x[0]  = *(const f32x4*)&zb[m][c];
        *(f32x4*)&x[4]  = *(const f32x4*)&zb[m][c + 4];
        *(f32x4*)&x[8]  = *(const f32x4*)&zb[m][c + 8];
        *(f32x4*)&x[12] = *(const f32x4*)&zb[m][c + 12];
        size_t go = (size_t)(base + m) * D + c;
#pragma unroll
        for (int i = 0; i < 16; ++i) x[i] = x[i] > 0.f ? x[i] : 0.f;
        unsigned wb[8];
#pragma unroll
        for (int j = 0; j < 8; ++j)
            wb[j] = (unsigned)f2bf(x[2 * j]) | ((unsigned)f2bf(x[2 * j + 1]) << 16);
        uint4* hp = (uint4*)(h_out + go);
        hp[0] = make_uint4(wb[0], wb[1], wb[2], wb[3]);
        hp[1] = make_uint4(wb[4], wb[5], wb[6], wb[7]);
        uint4 o8;
        o8.x = pk4(x[0], x[1], x[2], x[3]);
        o8.y = pk4(x[4], x[5], x[6], x[7]);
        o8.z = pk4(x[8], x[9], x[10], x[11]);
        o8.w = pk4(x[12], x[13], x[14], x[15]);
        *(uint4*)(h8_out + go) = o8;
    }
}

extern "C" void kernel_launch(void* const* d_in, const int* in_sizes, int n_in,
                              void* d_out, int out_size, void* d_ws, size_t ws_size,
                              hipStream_t stream) {
    const float* feats = (const float*)d_in[0];
    const int* neigh   = (const int*)d_in[1];
    const float* Ws    = (const float*)d_in[2];
    const float* bs    = (const float*)d_in[3];
    float* out = (float*)d_out;

    char* ws = (char*)d_ws;
    unsigned short* h1_bf  = (unsigned short*)(ws);                 // 25,600,000 B
    unsigned char*  feats8 = (unsigned char*)(ws + 25600000);       // 12,800,000 B
    unsigned char*  h18    = (unsigned char*)(ws + 38400000);       // 12,800,000 B
    unsigned short* Wt     = (unsigned short*)(ws + 51200000);      //    131,072 B

    cvt_all<<<3125, 256, 0, stream>>>(feats, Ws, (unsigned*)feats8, Wt);

    sage_layer<0><<<N_NODES / MB, 256, 0, stream>>>(
        feats, nullptr, feats8, neigh, Wt, bs, h1_bf, h18, nullptr);
    sage_layer<1><<<N_NODES / MB, 256, 0, stream>>>(
        nullptr, h1_bf, h18, neigh + N_NODES * K, Wt + CATK * D, bs + D,
        nullptr, nullptr, out);
}